// Round 1
// baseline (2143.457 us; speedup 1.0000x reference)
//
#include <hip/hip_runtime.h>
#include <math.h>

#define B_   8
#define C_   256
#define H_   64
#define W_   64
#define O_   256
#define KK_  9
#define CK_  2304      // C_*KK_
#define HW_  4096      // H_*W_
#define BN_EPS 1e-5f

#define P_   8         // pixels per block in main kernel
#define SP_  2312      // padded S row stride (bf16 elems): 2304+8, keeps 8B align, spreads banks

static __device__ __forceinline__ unsigned short f2bf(float f) {
    unsigned int u = __float_as_uint(f);
    unsigned int r = (u + 0x7fffu + ((u >> 16) & 1u)) >> 16;
    return (unsigned short)r;
}
static __device__ __forceinline__ float bf2f(unsigned short v) {
    return __uint_as_float(((unsigned int)v) << 16);
}

// ---------------- kernel 0: transpose w [O][CK] -> wT [CK][O] ----------------
__global__ __launch_bounds__(256) void transpose_w_kernel(
    const float* __restrict__ w, float* __restrict__ wT)
{
    int idx = blockIdx.x * 256 + threadIdx.x;   // grid covers O_*CK_ exactly
    int o  = idx / CK_;
    int ck = idx - o * CK_;
    wT[ck * O_ + o] = w[idx];
}

// ---------------- kernel 1: offset conv (27ch, 3x3, pad1) + sigmoid(mod) ----
// grid: B_*H_ blocks, 256 threads = 4 waves (c-split) x 64 (w)
__global__ __launch_bounds__(256) void offset_conv_kernel(
    const float* __restrict__ x, const float* __restrict__ w_off,
    const float* __restrict__ b_off, float* __restrict__ om)
{
    __shared__ float wbuf[4][8 * 243];   // per-wave staging of w_off slice
    __shared__ float red[4][64][27];

    const int b   = blockIdx.x >> 6;
    const int h   = blockIdx.x & 63;
    const int tid = threadIdx.x;
    const int w   = tid & 63;
    const int cg  = tid >> 6;

    float acc[27];
#pragma unroll
    for (int t = 0; t < 27; ++t) acc[t] = 0.f;

    for (int chunk = 0; chunk < 8; ++chunk) {
        const int cbase = cg * 64 + chunk * 8;
        // stage w_off[t][cbase+cl][k] -> wbuf[cg][cl*243 + t*9 + k]
        for (int i = w; i < 8 * 243; i += 64) {
            int cl = i / 243;
            int tk = i - cl * 243;
            int t  = tk / 9;
            int k  = tk - t * 9;
            wbuf[cg][i] = w_off[t * CK_ + (cbase + cl) * 9 + k];
        }
        __syncthreads();
        for (int cl = 0; cl < 8; ++cl) {
            const int c = cbase + cl;
            const float* xb = x + ((b * C_ + c) * HW_);
            float v[9];
#pragma unroll
            for (int r = 0; r < 3; ++r) {
                int hh = h - 1 + r;
                bool rok = (hh >= 0) && (hh < H_);
#pragma unroll
                for (int dc = 0; dc < 3; ++dc) {
                    int ww = w - 1 + dc;
                    v[r * 3 + dc] = (rok && ww >= 0 && ww < W_) ? xb[hh * W_ + ww] : 0.f;
                }
            }
            const float* wb = &wbuf[cg][cl * 243];
#pragma unroll
            for (int t = 0; t < 27; ++t) {
#pragma unroll
                for (int k = 0; k < 9; ++k)
                    acc[t] = fmaf(v[k], wb[t * 9 + k], acc[t]);
            }
        }
        __syncthreads();
    }

#pragma unroll
    for (int t = 0; t < 27; ++t) red[cg][w][t] = acc[t];
    __syncthreads();
    if (tid < 64) {
#pragma unroll
        for (int t = 0; t < 27; ++t) {
            float s = red[0][w][t] + red[1][w][t] + red[2][w][t] + red[3][w][t] + b_off[t];
            if (t >= 18) s = 1.f / (1.f + expf(-s));   // sigmoid on mod channels
            om[(b * 27 + t) * HW_ + h * W_ + w] = s;
        }
    }
}

// ---------------- kernel 2: sample (bilinear, modulated) + GEMM + BN + ReLU -
// grid: B_*H_*W_/P_ = 4096 blocks, 256 threads
__global__ __launch_bounds__(256) void dcn_main_kernel(
    const float* __restrict__ x, const float* __restrict__ om,
    const float* __restrict__ wT, const float* __restrict__ bias,
    const float* __restrict__ gamma, const float* __restrict__ beta,
    const float* __restrict__ rmean, const float* __restrict__ rvar,
    float* __restrict__ out)
{
    __shared__ unsigned short S[P_][SP_];   // sampled*mod, bf16, [p][c*9+k]
    __shared__ float offs[P_][27];          // dy(9), dx(9), mod(9) per pixel

    const int blk = blockIdx.x;
    const int b   = blk >> 9;           // 512 blocks per batch
    const int rem = blk & 511;
    const int h   = rem >> 3;
    const int w0  = (rem & 7) * P_;
    const int tid = threadIdx.x;

    if (tid < P_ * 27) {
        int p = tid / 27;
        int r = tid - p * 27;
        offs[p][r] = om[(b * 27 + r) * HW_ + h * W_ + (w0 + p)];
    }
    __syncthreads();

    // phase 1: bilinear sampling, one channel per thread
    {
        const int c = tid;
        const float* xb = x + ((b * C_ + c) * HW_);
        for (int p = 0; p < P_; ++p) {
            const int wpix = w0 + p;
#pragma unroll
            for (int k = 0; k < KK_; ++k) {
                const int ky = k / 3, kx = k - (k / 3) * 3;
                float py = (float)(h - 1 + ky) + offs[p][k];
                float px = (float)(wpix - 1 + kx) + offs[p][9 + k];
                float mod = offs[p][18 + k];
                float y0f = floorf(py), x0f = floorf(px);
                int y0 = (int)y0f, x0 = (int)x0f;
                float fy = py - y0f, fx = px - x0f;
                int y0c = min(max(y0, 0), H_ - 1);
                int y1c = min(max(y0 + 1, 0), H_ - 1);
                int x0c = min(max(x0, 0), W_ - 1);
                int x1c = min(max(x0 + 1, 0), W_ - 1);
                float vy0 = (y0 >= 0 && y0 < H_) ? 1.f : 0.f;
                float vy1 = (y0 + 1 >= 0 && y0 + 1 < H_) ? 1.f : 0.f;
                float vx0 = (x0 >= 0 && x0 < W_) ? 1.f : 0.f;
                float vx1 = (x0 + 1 >= 0 && x0 + 1 < W_) ? 1.f : 0.f;
                float s = xb[y0c * W_ + x0c] * ((1.f - fy) * (1.f - fx) * vy0 * vx0)
                        + xb[y0c * W_ + x1c] * ((1.f - fy) * fx        * vy0 * vx1)
                        + xb[y1c * W_ + x0c] * (fy        * (1.f - fx) * vy1 * vx0)
                        + xb[y1c * W_ + x1c] * (fy        * fx         * vy1 * vx1);
                S[p][c * KK_ + k] = f2bf(s * mod);
            }
        }
    }
    __syncthreads();

    // phase 2: out[o, p] = sum_ck wT[ck][o] * S[p][ck]; micro-tile 4(o) x 2(p)
    const int og = tid & 63;
    const int pg = tid >> 6;
    const int p0 = pg * 2;
    float acc[4][2];
#pragma unroll
    for (int i = 0; i < 4; ++i) { acc[i][0] = 0.f; acc[i][1] = 0.f; }

    const unsigned short* s0p = &S[p0][0];
    const unsigned short* s1p = &S[p0 + 1][0];

    for (int ck = 0; ck < CK_; ck += 4) {
        const ushort4 u0 = *(const ushort4*)(s0p + ck);
        const ushort4 u1 = *(const ushort4*)(s1p + ck);
        float sv0[4] = { bf2f(u0.x), bf2f(u0.y), bf2f(u0.z), bf2f(u0.w) };
        float sv1[4] = { bf2f(u1.x), bf2f(u1.y), bf2f(u1.z), bf2f(u1.w) };
#pragma unroll
        for (int q = 0; q < 4; ++q) {
            const float4 wq = *(const float4*)&wT[(ck + q) * O_ + og * 4];
            acc[0][0] = fmaf(wq.x, sv0[q], acc[0][0]);
            acc[1][0] = fmaf(wq.y, sv0[q], acc[1][0]);
            acc[2][0] = fmaf(wq.z, sv0[q], acc[2][0]);
            acc[3][0] = fmaf(wq.w, sv0[q], acc[3][0]);
            acc[0][1] = fmaf(wq.x, sv1[q], acc[0][1]);
            acc[1][1] = fmaf(wq.y, sv1[q], acc[1][1]);
            acc[2][1] = fmaf(wq.z, sv1[q], acc[2][1]);
            acc[3][1] = fmaf(wq.w, sv1[q], acc[3][1]);
        }
    }

    // epilogue: conv bias + BN + ReLU
#pragma unroll
    for (int i = 0; i < 4; ++i) {
        const int o = og * 4 + i;
        const float inv   = gamma[o] * rsqrtf(rvar[o] + BN_EPS);
        const float shift = beta[o] + (bias[o] - rmean[o]) * inv;
#pragma unroll
        for (int j = 0; j < 2; ++j) {
            float v = acc[i][j] * inv + shift;
            out[(b * O_ + o) * HW_ + h * W_ + (w0 + p0 + j)] = v > 0.f ? v : 0.f;
        }
    }
}

extern "C" void kernel_launch(void* const* d_in, const int* in_sizes, int n_in,
                              void* d_out, int out_size, void* d_ws, size_t ws_size,
                              hipStream_t stream) {
    const float* x     = (const float*)d_in[0];
    const float* w_off = (const float*)d_in[1];
    const float* b_off = (const float*)d_in[2];
    const float* w     = (const float*)d_in[3];
    const float* bias  = (const float*)d_in[4];
    const float* gamma = (const float*)d_in[5];
    const float* beta  = (const float*)d_in[6];
    const float* rmean = (const float*)d_in[7];
    const float* rvar  = (const float*)d_in[8];
    float* out = (float*)d_out;

    float* om = (float*)d_ws;                 // B*27*HW = 884736 floats
    float* wT = om + (size_t)B_ * 27 * HW_;   // CK*O   = 589824 floats

    transpose_w_kernel<<<(O_ * CK_) / 256, 256, 0, stream>>>(w, wT);
    offset_conv_kernel<<<B_ * H_, 256, 0, stream>>>(x, w_off, b_off, om);
    dcn_main_kernel<<<(B_ * HW_) / P_, 256, 0, stream>>>(
        x, om, wT, bias, gamma, beta, rmean, rvar, out);
}

// Round 2
// 512.219 us; speedup vs baseline: 4.1846x; 4.1846x over previous
//
#include <hip/hip_runtime.h>
#include <math.h>

#define B_   8
#define C_   256
#define H_   64
#define W_   64
#define O_   256
#define KK_  9
#define CK_  2304      // C_*KK_
#define HW_  4096      // H_*W_
#define BN_EPS 1e-5f

typedef __bf16 bf16x8 __attribute__((ext_vector_type(8)));
typedef float  f32x4  __attribute__((ext_vector_type(4)));

static __device__ __forceinline__ unsigned short f2bf(float f) {
    unsigned int u = __float_as_uint(f);
    unsigned int r = (u + 0x7fffu + ((u >> 16) & 1u)) >> 16;
    return (unsigned short)r;
}

// ---------------- kernel 0: repack w [O][C][9] -> wK [O][k*256+c] bf16 ------
__global__ __launch_bounds__(256) void repack_w_kernel(
    const float* __restrict__ w, unsigned short* __restrict__ wK)
{
    int idx = blockIdx.x * 256 + threadIdx.x;   // grid covers O_*CK_ exactly
    int o  = idx / CK_;
    int kp = idx - o * CK_;       // kappa = k*256 + c
    int k  = kp >> 8;
    int c  = kp & 255;
    wK[idx] = f2bf(w[o * CK_ + c * KK_ + k]);
}

// ---------------- kernel 1: offset conv (27ch, 3x3, pad1) + sigmoid(mod) ----
__global__ __launch_bounds__(256) void offset_conv_kernel(
    const float* __restrict__ x, const float* __restrict__ w_off,
    const float* __restrict__ b_off, float* __restrict__ om)
{
    __shared__ float wbuf[4][8 * 243];
    __shared__ float red[4][64][27];

    const int b   = blockIdx.x >> 6;
    const int h   = blockIdx.x & 63;
    const int tid = threadIdx.x;
    const int w   = tid & 63;
    const int cg  = tid >> 6;

    float acc[27];
#pragma unroll
    for (int t = 0; t < 27; ++t) acc[t] = 0.f;

    for (int chunk = 0; chunk < 8; ++chunk) {
        const int cbase = cg * 64 + chunk * 8;
        for (int i = w; i < 8 * 243; i += 64) {
            int cl = i / 243;
            int tk = i - cl * 243;
            int t  = tk / 9;
            int k  = tk - t * 9;
            wbuf[cg][i] = w_off[t * CK_ + (cbase + cl) * 9 + k];
        }
        __syncthreads();
        for (int cl = 0; cl < 8; ++cl) {
            const int c = cbase + cl;
            const float* xb = x + ((b * C_ + c) * HW_);
            float v[9];
#pragma unroll
            for (int r = 0; r < 3; ++r) {
                int hh = h - 1 + r;
                bool rok = (hh >= 0) && (hh < H_);
#pragma unroll
                for (int dc = 0; dc < 3; ++dc) {
                    int ww = w - 1 + dc;
                    v[r * 3 + dc] = (rok && ww >= 0 && ww < W_) ? xb[hh * W_ + ww] : 0.f;
                }
            }
            const float* wb = &wbuf[cg][cl * 243];
#pragma unroll
            for (int t = 0; t < 27; ++t) {
#pragma unroll
                for (int k = 0; k < 9; ++k)
                    acc[t] = fmaf(v[k], wb[t * 9 + k], acc[t]);
            }
        }
        __syncthreads();
    }

#pragma unroll
    for (int t = 0; t < 27; ++t) red[cg][w][t] = acc[t];
    __syncthreads();
    if (tid < 64) {
#pragma unroll
        for (int t = 0; t < 27; ++t) {
            float s = red[0][w][t] + red[1][w][t] + red[2][w][t] + red[3][w][t] + b_off[t];
            if (t >= 18) s = 1.f / (1.f + expf(-s));
            om[(b * 27 + t) * HW_ + h * W_ + w] = s;
        }
    }
}

// ---------------- kernel 2: fused sample + MFMA GEMM + BN + ReLU ------------
// grid: B_*H_ = 512 blocks, 256 threads = 4 waves.
// Block tile: 64 pixels (row h, w=0..63) x 256 outputs.
// Wave i: all 64 px (4 m-tiles) x o in [i*64, i*64+64) (4 n-tiles).
__global__ __launch_bounds__(256, 2) void dcn_mfma_kernel(
    const float* __restrict__ x, const float* __restrict__ om,
    const unsigned short* __restrict__ wK,
    const float* __restrict__ bias, const float* __restrict__ gamma,
    const float* __restrict__ beta, const float* __restrict__ rmean,
    const float* __restrict__ rvar, float* __restrict__ out)
{
    __shared__ unsigned short S[64][72];   // [pixel][k-local], bf16, stride 72 (16B-aligned rows)
    __shared__ float4 wgtv[576];           // per (pixel,tap): mod-folded bilinear weights
    __shared__ int4   idxv[576];           // per (pixel,tap): clamped corner indices

    const int blk  = blockIdx.x;
    const int b    = blk >> 6;
    const int h    = blk & 63;
    const int tid  = threadIdx.x;
    const int lane = tid & 63;
    const int wave = tid >> 6;
    const int m16  = lane & 15;   // free-dim index within a 16-tile (m for A, n for B)
    const int q    = lane >> 4;   // k-quad

    // ---- precompute bilinear weights + indices per (pixel, tap) ----
    for (int i = tid; i < 576; i += 256) {
        int p = i / 9;
        int t = i - p * 9;
        const int base = h * W_ + p;
        float dy = om[(b * 27 +      t) * HW_ + base];
        float dx = om[(b * 27 +  9 + t) * HW_ + base];
        float md = om[(b * 27 + 18 + t) * HW_ + base];
        float py = (float)(h - 1 + t / 3) + dy;
        float px = (float)(p - 1 + t % 3) + dx;
        float y0f = floorf(py), x0f = floorf(px);
        int   y0 = (int)y0f,    x0 = (int)x0f;
        float fy = py - y0f,    fx = px - x0f;
        int y0c = min(max(y0,     0), H_ - 1), y1c = min(max(y0 + 1, 0), H_ - 1);
        int x0c = min(max(x0,     0), W_ - 1), x1c = min(max(x0 + 1, 0), W_ - 1);
        float vy0 = (y0     >= 0 && y0     < H_) ? 1.f : 0.f;
        float vy1 = (y0 + 1 >= 0 && y0 + 1 < H_) ? 1.f : 0.f;
        float vx0 = (x0     >= 0 && x0     < W_) ? 1.f : 0.f;
        float vx1 = (x0 + 1 >= 0 && x0 + 1 < W_) ? 1.f : 0.f;
        wgtv[i] = make_float4((1.f - fy) * (1.f - fx) * vy0 * vx0 * md,
                              (1.f - fy) * fx         * vy0 * vx1 * md,
                              fy         * (1.f - fx) * vy1 * vx0 * md,
                              fy         * fx         * vy1 * vx1 * md);
        idxv[i] = make_int4(y0c * W_ + x0c, y0c * W_ + x1c,
                            y1c * W_ + x0c, y1c * W_ + x1c);
    }
    __syncthreads();

    const int p  = lane;          // sampling: pixel per lane
    const int g  = wave;          // sampling: channel subgroup per wave
    const int o0 = wave * 64;     // MFMA: o-range per wave

    f32x4 acc[4][4];
#pragma unroll
    for (int mi = 0; mi < 4; ++mi)
#pragma unroll
        for (int nj = 0; nj < 4; ++nj)
#pragma unroll
            for (int r = 0; r < 4; ++r) acc[mi][nj][r] = 0.f;

    for (int tap = 0; tap < 9; ++tap) {
        const float4 wq = wgtv[p * 9 + tap];
        const int4   iq = idxv[p * 9 + tap];
        for (int sub = 0; sub < 8; ++sub) {
            const int c0   = sub * 32;
            const int kap0 = tap * 256 + c0;

            // B prefetch: 4 n-tiles, 16B/lane, contiguous rows of wK (L2-resident)
            uint4 braw[4];
#pragma unroll
            for (int nj = 0; nj < 4; ++nj) {
                const int o = o0 + nj * 16 + m16;
                braw[nj] = *(const uint4*)&wK[(size_t)o * CK_ + kap0 + q * 8];
            }

            // sample 8 channels (c0+g*8 .. +8) for pixel p
            const float* xb = x + ((size_t)(b * C_ + c0 + g * 8) * HW_);
            unsigned int pk[4];
#pragma unroll
            for (int jj = 0; jj < 4; ++jj) {
                float v0 = xb[iq.x] * wq.x + xb[iq.y] * wq.y
                         + xb[iq.z] * wq.z + xb[iq.w] * wq.w;
                xb += HW_;
                float v1 = xb[iq.x] * wq.x + xb[iq.y] * wq.y
                         + xb[iq.z] * wq.z + xb[iq.w] * wq.w;
                xb += HW_;
                pk[jj] = (unsigned int)f2bf(v0) | ((unsigned int)f2bf(v1) << 16);
            }

            __syncthreads();   // prior chunk's a-frag reads complete
            *(uint4*)&S[p][g * 8] = make_uint4(pk[0], pk[1], pk[2], pk[3]);
            __syncthreads();   // S tile visible

            // MFMA: 4 m-tiles x 4 n-tiles, one K=32 step
            bf16x8 a[4];
#pragma unroll
            for (int mi = 0; mi < 4; ++mi)
                a[mi] = *(const bf16x8*)&S[mi * 16 + m16][q * 8];
#pragma unroll
            for (int nj = 0; nj < 4; ++nj) {
                bf16x8 bb = __builtin_bit_cast(bf16x8, braw[nj]);
#pragma unroll
                for (int mi = 0; mi < 4; ++mi)
                    acc[mi][nj] = __builtin_amdgcn_mfma_f32_16x16x32_bf16(
                        a[mi], bb, acc[mi][nj], 0, 0, 0);
            }
        }
    }

    // epilogue: conv bias + BN + ReLU, float4 stores
#pragma unroll
    for (int nj = 0; nj < 4; ++nj) {
        const int o   = o0 + nj * 16 + m16;
        const float inv = gamma[o] * rsqrtf(rvar[o] + BN_EPS);
        const float sh  = beta[o] + (bias[o] - rmean[o]) * inv;
        float* ob = out + ((size_t)(b * O_ + o) * HW_ + h * W_);
#pragma unroll
        for (int mi = 0; mi < 4; ++mi) {
            f32x4 v = acc[mi][nj];
            float4 r;
            r.x = fmaxf(v[0] * inv + sh, 0.f);
            r.y = fmaxf(v[1] * inv + sh, 0.f);
            r.z = fmaxf(v[2] * inv + sh, 0.f);
            r.w = fmaxf(v[3] * inv + sh, 0.f);
            *(float4*)&ob[mi * 16 + q * 4] = r;
        }
    }
}

extern "C" void kernel_launch(void* const* d_in, const int* in_sizes, int n_in,
                              void* d_out, int out_size, void* d_ws, size_t ws_size,
                              hipStream_t stream) {
    const float* x     = (const float*)d_in[0];
    const float* w_off = (const float*)d_in[1];
    const float* b_off = (const float*)d_in[2];
    const float* w     = (const float*)d_in[3];
    const float* bias  = (const float*)d_in[4];
    const float* gamma = (const float*)d_in[5];
    const float* beta  = (const float*)d_in[6];
    const float* rmean = (const float*)d_in[7];
    const float* rvar  = (const float*)d_in[8];
    float* out = (float*)d_out;

    float*          om = (float*)d_ws;                          // 884736 floats
    unsigned short* wK = (unsigned short*)(om + (size_t)B_ * 27 * HW_); // 589824 bf16

    repack_w_kernel<<<(O_ * CK_) / 256, 256, 0, stream>>>(w, wK);
    offset_conv_kernel<<<B_ * H_, 256, 0, stream>>>(x, w_off, b_off, om);
    dcn_mfma_kernel<<<B_ * H_, 256, 0, stream>>>(
        x, om, wK, bias, gamma, beta, rmean, rvar, out);
}

// Round 3
// 381.017 us; speedup vs baseline: 5.6256x; 1.3443x over previous
//
#include <hip/hip_runtime.h>
#include <math.h>

#define B_   8
#define C_   256
#define H_   64
#define W_   64
#define O_   256
#define KK_  9
#define CK_  2304      // C_*KK_
#define HW_  4096      // H_*W_
#define BN_EPS 1e-5f

typedef __bf16 bf16x8 __attribute__((ext_vector_type(8)));
typedef float  f32x4  __attribute__((ext_vector_type(4)));

static __device__ __forceinline__ unsigned short f2bf(float f) {
    unsigned int u = __float_as_uint(f);
    unsigned int r = (u + 0x7fffu + ((u >> 16) & 1u)) >> 16;
    return (unsigned short)r;
}
static __device__ __forceinline__ float bflo(unsigned int u) {
    return __uint_as_float(u << 16);
}
static __device__ __forceinline__ float bfhi(unsigned int u) {
    return __uint_as_float(u & 0xffff0000u);
}

// ---- kernel 0: repack w -> wKf (MFMA B-frag tile order, bf16)
//                repack w_off -> wo3[c][t*9+k] (coalesced staging for offset conv)
__global__ __launch_bounds__(256) void repack_kernel(
    const float* __restrict__ w, const float* __restrict__ w_off,
    unsigned short* __restrict__ wKf, float* __restrict__ wo3)
{
    int blk = blockIdx.x;
    if (blk < 2304) {
        int idx = blk * 256 + threadIdx.x;       // linear packed index
        int NT  = idx / 36864;                   // o-tile (16 o's), 72*512 per tile
        int r   = idx - NT * 36864;
        int KC  = r >> 9;                        // k-chunk (32 kappa)
        int r2  = r & 511;
        int lane = r2 >> 3, e = r2 & 7;
        int n16 = lane & 15, q = lane >> 4;
        int o   = NT * 16 + n16;
        int kap = KC * 32 + q * 8 + e;           // kappa = tap*256 + c
        int tap = kap >> 8, c = kap & 255;
        wKf[idx] = f2bf(w[(o * C_ + c) * KK_ + tap]);
    } else {
        int idx = (blk - 2304) * 256 + threadIdx.x;  // 0..62207
        int c = idx / 243, tk = idx - c * 243;
        int t = tk / 9, k = tk - t * 9;
        wo3[idx] = w_off[(t * C_ + c) * KK_ + k];
    }
}

// ---- kernel 1: transpose x [b][c][hw] f32 -> xT [b][hw][c] bf16 (NHWC)
__global__ __launch_bounds__(256) void transpose_x_kernel(
    const float* __restrict__ x, unsigned short* __restrict__ xT)
{
    __shared__ float tile[64][65];
    const int blk = blockIdx.x;
    const int ct  = blk & 3;
    const int hwt = (blk >> 2) & 63;
    const int b   = blk >> 8;
    const int c0  = ct * 64, hw0 = hwt * 64;
    const int tl  = threadIdx.x & 63, tg = threadIdx.x >> 6;
#pragma unroll
    for (int r = 0; r < 16; ++r) {
        int c_l = tg + r * 4;
        tile[c_l][tl] = x[((size_t)(b * C_ + c0 + c_l)) * HW_ + hw0 + tl];
    }
    __syncthreads();
#pragma unroll
    for (int r = 0; r < 16; ++r) {
        int hw_l = tg + r * 4;
        xT[((size_t)(b * HW_ + hw0 + hw_l)) * C_ + c0 + tl] = f2bf(tile[tl][hw_l]);
    }
}

// ---- kernel 2: offset conv, c-split x2 across blocks, partials to pom
__global__ __launch_bounds__(256) void offset_conv_kernel(
    const float* __restrict__ x, const float* __restrict__ wo3,
    float* __restrict__ pom)
{
    __shared__ float smem[7776];      // wbuf 4x1944, later reused as red 4x64x27

    const int blk   = blockIdx.x;     // (b*64+h)*2 + chalf
    const int chalf = blk & 1;
    const int bh    = blk >> 1;
    const int b = bh >> 6, h = bh & 63;
    const int tid = threadIdx.x, wl = tid & 63, cg = tid >> 6;
    float* wbuf = &smem[cg * 1944];

    float acc[27];
#pragma unroll
    for (int t = 0; t < 27; ++t) acc[t] = 0.f;

    for (int chunk = 0; chunk < 4; ++chunk) {
        const int cbase = chalf * 128 + cg * 32 + chunk * 8;
        for (int i = wl; i < 1944; i += 64)          // coalesced: wo3 rows contiguous
            wbuf[i] = wo3[cbase * 243 + i];
        // wave-local LDS write->read: compiler-inserted lgkmcnt, no barrier needed
        for (int cl = 0; cl < 8; ++cl) {
            const int c = cbase + cl;
            const float* xb = x + ((size_t)(b * C_ + c)) * HW_;
            float v[9];
#pragma unroll
            for (int r = 0; r < 3; ++r) {
                int hh = h - 1 + r;
                bool rok = (hh >= 0) && (hh < H_);
#pragma unroll
                for (int dc = 0; dc < 3; ++dc) {
                    int ww = wl - 1 + dc;
                    v[r * 3 + dc] = (rok && ww >= 0 && ww < W_) ? xb[hh * W_ + ww] : 0.f;
                }
            }
            const float* wb = &wbuf[cl * 243];
#pragma unroll
            for (int t = 0; t < 27; ++t) {
#pragma unroll
                for (int k = 0; k < 9; ++k)
                    acc[t] = fmaf(v[k], wb[t * 9 + k], acc[t]);
            }
        }
    }

    __syncthreads();                  // all waves done with wbuf
#pragma unroll
    for (int t = 0; t < 27; ++t) smem[(cg * 64 + wl) * 27 + t] = acc[t];
    __syncthreads();
    if (tid < 64) {
#pragma unroll
        for (int t = 0; t < 27; ++t) {
            float s = smem[(0 * 64 + wl) * 27 + t] + smem[(1 * 64 + wl) * 27 + t]
                    + smem[(2 * 64 + wl) * 27 + t] + smem[(3 * 64 + wl) * 27 + t];
            pom[(((size_t)chalf * B_ + b) * 27 + t) * HW_ + h * W_ + wl] = s;
        }
    }
}

// ---- kernel 3: sum c-halves + bias, sigmoid on mod channels -> om
__global__ __launch_bounds__(256) void offset_final_kernel(
    const float* __restrict__ pom, const float* __restrict__ b_off,
    float* __restrict__ om)
{
    int idx = blockIdx.x * 256 + threadIdx.x;    // < 884736
    int t = (idx >> 12) % 27;
    float s = pom[idx] + pom[884736 + idx] + b_off[t];
    if (t >= 18) s = 1.f / (1.f + expf(-s));
    om[idx] = s;
}

// ---- kernel 4: fused sample (bf16 NHWC gathers) + MFMA GEMM + BN + ReLU
// grid: 1024 blocks = (b,h) x o-half. Block: 64 px x 128 o, 4 waves.
// Wave = 64 px x 32 o (4 m-tiles x 2 n-tiles). Wave w samples m-tile w.
__global__ __launch_bounds__(256, 4) void dcn_mfma_kernel(
    const unsigned short* __restrict__ xT, const float* __restrict__ om,
    const unsigned short* __restrict__ wKf,
    const float* __restrict__ bias, const float* __restrict__ gamma,
    const float* __restrict__ beta, const float* __restrict__ rmean,
    const float* __restrict__ rvar, float* __restrict__ out)
{
    __shared__ float4 wgtv[576];                 // (px, tap): mod-folded bilinear weights
    __shared__ int4   idxv[576];                 // (px, tap): corner BYTE offsets into xT
    __shared__ unsigned short Abuf[4][64][8];    // A-frags: [mtile][lane][8 bf16]

    const int blk   = blockIdx.x;
    const int ohalf = blk & 1;
    const int bh    = blk >> 1;
    const int b = bh >> 6, h = bh & 63;
    const int tid = threadIdx.x, lane = tid & 63, wave = tid >> 6;

    // ---- per-(pixel,tap) tables ----
    for (int i = tid; i < 576; i += 256) {
        int p = i / 9, t = i - p * 9;
        const int pos = h * W_ + p;
        float dy = om[(b * 27 +      t) * HW_ + pos];
        float dx = om[(b * 27 +  9 + t) * HW_ + pos];
        float md = om[(b * 27 + 18 + t) * HW_ + pos];
        float py = (float)(h - 1 + t / 3) + dy;
        float px = (float)(p - 1 + t % 3) + dx;
        float y0f = floorf(py), x0f = floorf(px);
        int   y0 = (int)y0f,    x0 = (int)x0f;
        float fy = py - y0f,    fx = px - x0f;
        int y0c = min(max(y0,     0), H_ - 1), y1c = min(max(y0 + 1, 0), H_ - 1);
        int x0c = min(max(x0,     0), W_ - 1), x1c = min(max(x0 + 1, 0), W_ - 1);
        float vy0 = (y0     >= 0 && y0     < H_) ? 1.f : 0.f;
        float vy1 = (y0 + 1 >= 0 && y0 + 1 < H_) ? 1.f : 0.f;
        float vx0 = (x0     >= 0 && x0     < W_) ? 1.f : 0.f;
        float vx1 = (x0 + 1 >= 0 && x0 + 1 < W_) ? 1.f : 0.f;
        wgtv[i] = make_float4((1.f - fy) * (1.f - fx) * vy0 * vx0 * md,
                              (1.f - fy) * fx         * vy0 * vx1 * md,
                              fy         * (1.f - fx) * vy1 * vx0 * md,
                              fy         * fx         * vy1 * vx1 * md);
        const int rowb = (b * HW_) * (C_ * 2);       // byte offset of batch b in xT
        idxv[i] = make_int4(rowb + (y0c * W_ + x0c) * (C_ * 2),
                            rowb + (y0c * W_ + x1c) * (C_ * 2),
                            rowb + (y1c * W_ + x0c) * (C_ * 2),
                            rowb + (y1c * W_ + x1c) * (C_ * 2));
    }
    __syncthreads();

    const int pix = wave * 16 + (lane & 15);    // sampling: pixel this thread feeds
    const int s_q = lane >> 4;                  // sampling: channel 8-group

    f32x4 acc[4][2];
#pragma unroll
    for (int mi = 0; mi < 4; ++mi)
#pragma unroll
        for (int nj = 0; nj < 2; ++nj)
#pragma unroll
            for (int r = 0; r < 4; ++r) acc[mi][nj][r] = 0.f;

    const uint4* wKf4 = (const uint4*)wKf;
    const char*  xTb  = (const char*)xT;

    for (int tap = 0; tap < 9; ++tap) {
        const float4 wq = wgtv[pix * 9 + tap];
        const int4   iq = idxv[pix * 9 + tap];
        for (int cc = 0; cc < 8; ++cc) {
            const int KC = tap * 8 + cc;

            // B prefetch: 2 n-tiles, wave-contiguous 1 KB bursts (frag-packed)
            uint4 braw[2];
#pragma unroll
            for (int nj = 0; nj < 2; ++nj) {
                const int NT = ohalf * 8 + wave * 2 + nj;
                braw[nj] = wKf4[(size_t)(NT * 72 + KC) * 64 + lane];
            }

            // sample 8 channels of pixel `pix`: 4 vector corner loads (16 B each)
            const int cof = cc * 64 + s_q * 16;
            const uint4 k0 = *(const uint4*)(xTb + iq.x + cof);
            const uint4 k1 = *(const uint4*)(xTb + iq.y + cof);
            const uint4 k2 = *(const uint4*)(xTb + iq.z + cof);
            const uint4 k3 = *(const uint4*)(xTb + iq.w + cof);

            float f0 = wq.x * bflo(k0.x) + wq.y * bflo(k1.x) + wq.z * bflo(k2.x) + wq.w * bflo(k3.x);
            float f1 = wq.x * bfhi(k0.x) + wq.y * bfhi(k1.x) + wq.z * bfhi(k2.x) + wq.w * bfhi(k3.x);
            float f2 = wq.x * bflo(k0.y) + wq.y * bflo(k1.y) + wq.z * bflo(k2.y) + wq.w * bflo(k3.y);
            float f3 = wq.x * bfhi(k0.y) + wq.y * bfhi(k1.y) + wq.z * bfhi(k2.y) + wq.w * bfhi(k3.y);
            float f4 = wq.x * bflo(k0.z) + wq.y * bflo(k1.z) + wq.z * bflo(k2.z) + wq.w * bflo(k3.z);
            float f5 = wq.x * bfhi(k0.z) + wq.y * bfhi(k1.z) + wq.z * bfhi(k2.z) + wq.w * bfhi(k3.z);
            float f6 = wq.x * bflo(k0.w) + wq.y * bflo(k1.w) + wq.z * bflo(k2.w) + wq.w * bflo(k3.w);
            float f7 = wq.x * bfhi(k0.w) + wq.y * bfhi(k1.w) + wq.z * bfhi(k2.w) + wq.w * bfhi(k3.w);

            uint4 pk;
            pk.x = (unsigned int)f2bf(f0) | ((unsigned int)f2bf(f1) << 16);
            pk.y = (unsigned int)f2bf(f2) | ((unsigned int)f2bf(f3) << 16);
            pk.z = (unsigned int)f2bf(f4) | ((unsigned int)f2bf(f5) << 16);
            pk.w = (unsigned int)f2bf(f6) | ((unsigned int)f2bf(f7) << 16);

            __syncthreads();                     // previous step's A-frag reads done
            *(uint4*)&Abuf[wave][lane][0] = pk;  // frag layout, conflict-free
            __syncthreads();                     // tile visible

            bf16x8 a[4];
#pragma unroll
            for (int mi = 0; mi < 4; ++mi)
                a[mi] = *(const bf16x8*)&Abuf[mi][lane][0];
#pragma unroll
            for (int nj = 0; nj < 2; ++nj) {
                bf16x8 bb = __builtin_bit_cast(bf16x8, braw[nj]);
#pragma unroll
                for (int mi = 0; mi < 4; ++mi)
                    acc[mi][nj] = __builtin_amdgcn_mfma_f32_16x16x32_bf16(
                        a[mi], bb, acc[mi][nj], 0, 0, 0);
            }
        }
    }

    // ---- epilogue: conv bias + BN + ReLU, float4 stores ----
#pragma unroll
    for (int nj = 0; nj < 2; ++nj) {
        const int o = ohalf * 128 + wave * 32 + nj * 16 + (lane & 15);
        const float inv = gamma[o] * rsqrtf(rvar[o] + BN_EPS);
        const float sh  = beta[o] + (bias[o] - rmean[o]) * inv;
        float* ob = out + ((size_t)(b * O_ + o)) * HW_ + h * W_;
#pragma unroll
        for (int mi = 0; mi < 4; ++mi) {
            f32x4 v = acc[mi][nj];
            float4 r;
            r.x = fmaxf(v[0] * inv + sh, 0.f);
            r.y = fmaxf(v[1] * inv + sh, 0.f);
            r.z = fmaxf(v[2] * inv + sh, 0.f);
            r.w = fmaxf(v[3] * inv + sh, 0.f);
            *(float4*)&ob[mi * 16 + (lane >> 4) * 4] = r;
        }
    }
}

extern "C" void kernel_launch(void* const* d_in, const int* in_sizes, int n_in,
                              void* d_out, int out_size, void* d_ws, size_t ws_size,
                              hipStream_t stream) {
    const float* x     = (const float*)d_in[0];
    const float* w_off = (const float*)d_in[1];
    const float* b_off = (const float*)d_in[2];
    const float* w     = (const float*)d_in[3];
    const float* bias  = (const float*)d_in[4];
    const float* gamma = (const float*)d_in[5];
    const float* beta  = (const float*)d_in[6];
    const float* rmean = (const float*)d_in[7];
    const float* rvar  = (const float*)d_in[8];
    float* out = (float*)d_out;

    float* om  = (float*)d_ws;                   // 884736 f
    float* pom = om + 884736;                    // 1769472 f
    float* wo3 = pom + 1769472;                  // 62208 f
    unsigned short* wKf = (unsigned short*)(wo3 + 62208);   // 589824 bf16
    unsigned short* xT  = wKf + 589824;                     // 8388608 bf16

    repack_kernel<<<2547, 256, 0, stream>>>(w, w_off, wKf, wo3);
    transpose_x_kernel<<<2048, 256, 0, stream>>>(x, xT);
    offset_conv_kernel<<<1024, 256, 0, stream>>>(x, wo3, pom);
    offset_final_kernel<<<3456, 256, 0, stream>>>(pom, b_off, om);
    dcn_mfma_kernel<<<1024, 256, 0, stream>>>(
        xT, om, wKf, bias, gamma, beta, rmean, rvar, out);
}

// Round 5
// 225.881 us; speedup vs baseline: 9.4893x; 1.6868x over previous
//
#include <hip/hip_runtime.h>
#include <math.h>

#define B_   8
#define C_   256
#define H_   64
#define W_   64
#define O_   256
#define KK_  9
#define CK_  2304      // C_*KK_
#define HW_  4096      // H_*W_
#define BN_EPS 1e-5f

typedef __bf16 bf16x8 __attribute__((ext_vector_type(8)));
typedef float  f32x4  __attribute__((ext_vector_type(4)));

static __device__ __forceinline__ unsigned short f2bf(float f) {
    unsigned int u = __float_as_uint(f);
    unsigned int r = (u + 0x7fffu + ((u >> 16) & 1u)) >> 16;
    return (unsigned short)r;
}
static __device__ __forceinline__ float bflo(unsigned int u) {
    return __uint_as_float(u << 16);
}
static __device__ __forceinline__ float bfhi(unsigned int u) {
    return __uint_as_float(u & 0xffff0000u);
}
static __device__ __forceinline__ unsigned int pack2bf(float a, float b) {
    return (unsigned int)f2bf(a) | ((unsigned int)f2bf(b) << 16);
}

// ---- kernel 0: repack w -> wKf (MFMA B-frag order, 16 NT x 72 KC x 64 lane x 8)
//                repack w_off -> wof (same frag order, 2 NT, o>=27 zero-padded)
__global__ __launch_bounds__(256) void repack_kernel(
    const float* __restrict__ w, const float* __restrict__ w_off,
    unsigned short* __restrict__ wKf, unsigned short* __restrict__ wof)
{
    int blk = blockIdx.x;
    if (blk < 2304) {
        int idx = blk * 256 + threadIdx.x;
        int NT  = idx / 36864;
        int r   = idx - NT * 36864;
        int KC  = r >> 9;
        int r2  = r & 511;
        int lane = r2 >> 3, e = r2 & 7;
        int n16 = lane & 15, q = lane >> 4;
        int o   = NT * 16 + n16;
        int kap = KC * 32 + q * 8 + e;           // kappa = tap*256 + c
        int tap = kap >> 8, c = kap & 255;
        wKf[idx] = f2bf(w[(o * C_ + c) * KK_ + tap]);
    } else {
        int idx = (blk - 2304) * 256 + threadIdx.x;   // < 73728
        int NT  = idx / 36864;
        int r   = idx - NT * 36864;
        int KC  = r >> 9;
        int r2  = r & 511;
        int lane = r2 >> 3, e = r2 & 7;
        int n16 = lane & 15, q = lane >> 4;
        int o   = NT * 16 + n16;                 // 0..31, valid t<27
        int kap = KC * 32 + q * 8 + e;
        int tap = kap >> 8, c = kap & 255;
        wof[idx] = (o < 27) ? f2bf(w_off[(o * C_ + c) * KK_ + tap])
                            : (unsigned short)0;
    }
}

// ---- kernel 1: transpose x [b][c][hw] f32 -> xT [b][hw][c] bf16 (XCD-swizzled b)
__global__ __launch_bounds__(256) void transpose_x_kernel(
    const float* __restrict__ x, unsigned short* __restrict__ xT)
{
    __shared__ float tile[64][65];
    const int blk = blockIdx.x;
    const int b   = blk & 7;
    const int ct  = (blk >> 3) & 3;
    const int hwt = blk >> 5;
    const int c0  = ct * 64, hw0 = hwt * 64;
    const int tl  = threadIdx.x & 63, tg = threadIdx.x >> 6;
#pragma unroll
    for (int r = 0; r < 16; ++r) {
        int c_l = tg + r * 4;
        tile[c_l][tl] = x[((size_t)(b * C_ + c0 + c_l)) * HW_ + hw0 + tl];
    }
    __syncthreads();
#pragma unroll
    for (int r = 0; r < 16; ++r) {
        int hw_l = tg + r * 4;
        xT[((size_t)(b * HW_ + hw0 + hw_l)) * C_ + c0 + tl] = f2bf(tile[tl][hw_l]);
    }
}

// ---- kernel 2: offset conv via MFMA on xT + frag-packed wof, bias+sigmoid epilogue
// grid 512 = (b = blk&7) x (h = blk>>3); 256 thr, wave wv -> m-tile wv (16 px), 2 n-tiles
__global__ __launch_bounds__(256) void offset_mfma_kernel(
    const unsigned short* __restrict__ xT, const unsigned short* __restrict__ wof,
    const float* __restrict__ b_off, float* __restrict__ om)
{
    const int blk = blockIdx.x;
    const int b = blk & 7, h = blk >> 3;
    const int tid = threadIdx.x, lane = tid & 63, wv = tid >> 6;
    const int px = wv * 16 + (lane & 15);
    const int q  = lane >> 4;

    f32x4 acc[2];
#pragma unroll
    for (int nj = 0; nj < 2; ++nj)
#pragma unroll
        for (int r = 0; r < 4; ++r) acc[nj][r] = 0.f;

    const uint4* wof4 = (const uint4*)wof;

    for (int tap = 0; tap < 9; ++tap) {
        const int hh = h + tap / 3 - 1;
        const int ww = px + tap % 3 - 1;
        const bool valid = (hh >= 0) && (hh < H_) && (ww >= 0) && (ww < W_);
        const long base = ((long)(b * HW_ + hh * W_ + ww)) << 8;   // elem index
#pragma unroll
        for (int cc = 0; cc < 8; ++cc) {
            const int KC = tap * 8 + cc;
            uint4 araw = make_uint4(0u, 0u, 0u, 0u);
            if (valid) araw = *(const uint4*)&xT[base + cc * 32 + q * 8];
            bf16x8 a = __builtin_bit_cast(bf16x8, araw);
#pragma unroll
            for (int nj = 0; nj < 2; ++nj) {
                uint4 braw = wof4[(size_t)(nj * 72 + KC) * 64 + lane];
                acc[nj] = __builtin_amdgcn_mfma_f32_16x16x32_bf16(
                    a, __builtin_bit_cast(bf16x8, braw), acc[nj], 0, 0, 0);
            }
        }
    }

#pragma unroll
    for (int nj = 0; nj < 2; ++nj) {
        const int t = nj * 16 + (lane & 15);
        if (t < 27) {
            const float bo = b_off[t];
            f32x4 v = acc[nj];
            float4 r;
            float s0 = v[0] + bo, s1 = v[1] + bo, s2 = v[2] + bo, s3 = v[3] + bo;
            if (t >= 18) {
                s0 = 1.f / (1.f + expf(-s0));
                s1 = 1.f / (1.f + expf(-s1));
                s2 = 1.f / (1.f + expf(-s2));
                s3 = 1.f / (1.f + expf(-s3));
            }
            r.x = s0; r.y = s1; r.z = s2; r.w = s3;
            *(float4*)&om[((size_t)(b * 27 + t)) * HW_ + h * W_ + wv * 16 + q * 4] = r;
        }
    }
}

// ---- kernel 3: fused sample + MFMA GEMM + BN + ReLU
// grid 512 = (b = blk&7) x (h = blk>>3). Block = 64 px row x 256 o, 512 thr / 8 waves.
// Wave wv: all 64 px (4 m-tiles) x o in [wv*32, wv*32+32) (2 n-tiles).
// Sampling: lane = pixel, wave wv = channel window [wv*32, wv*32+32), per-tap staging.
__global__ __launch_bounds__(512, 4) void dcn_mfma_kernel(
    const unsigned short* __restrict__ xT, const float* __restrict__ om,
    const unsigned short* __restrict__ wKf,
    const float* __restrict__ bias, const float* __restrict__ gamma,
    const float* __restrict__ beta, const float* __restrict__ rmean,
    const float* __restrict__ rvar, float* __restrict__ out)
{
    __shared__ float4 wgtv[576];                  // (px,tap): mod-folded bilinear weights
    __shared__ int4   idxv[576];                  // (px,tap): corner BYTE offsets into xT
    __shared__ __align__(16) unsigned short Abuf[8][4][64][8];   // [cc][mi][lane][j] 32 KB

    const int blk = blockIdx.x;
    const int b = blk & 7, h = blk >> 3;
    const int tid = threadIdx.x, lane = tid & 63, wv = tid >> 6;

    // ---- per-(pixel,tap) tables ----
    for (int i = tid; i < 576; i += 512) {
        int p = i / 9, t = i - p * 9;
        const int pos = h * W_ + p;
        float dy = om[(b * 27 +      t) * HW_ + pos];
        float dx = om[(b * 27 +  9 + t) * HW_ + pos];
        float md = om[(b * 27 + 18 + t) * HW_ + pos];
        float py = (float)(h - 1 + t / 3) + dy;
        float px = (float)(p - 1 + t % 3) + dx;
        float y0f = floorf(py), x0f = floorf(px);
        int   y0 = (int)y0f,    x0 = (int)x0f;
        float fy = py - y0f,    fx = px - x0f;
        int y0c = min(max(y0,     0), H_ - 1), y1c = min(max(y0 + 1, 0), H_ - 1);
        int x0c = min(max(x0,     0), W_ - 1), x1c = min(max(x0 + 1, 0), W_ - 1);
        float vy0 = (y0     >= 0 && y0     < H_) ? 1.f : 0.f;
        float vy1 = (y0 + 1 >= 0 && y0 + 1 < H_) ? 1.f : 0.f;
        float vx0 = (x0     >= 0 && x0     < W_) ? 1.f : 0.f;
        float vx1 = (x0 + 1 >= 0 && x0 + 1 < W_) ? 1.f : 0.f;
        wgtv[i] = make_float4((1.f - fy) * (1.f - fx) * vy0 * vx0 * md,
                              (1.f - fy) * fx         * vy0 * vx1 * md,
                              fy         * (1.f - fx) * vy1 * vx0 * md,
                              fy         * fx         * vy1 * vx1 * md);
        const int rowb = (b * HW_) * (C_ * 2);
        idxv[i] = make_int4(rowb + (y0c * W_ + x0c) * (C_ * 2),
                            rowb + (y0c * W_ + x1c) * (C_ * 2),
                            rowb + (y1c * W_ + x0c) * (C_ * 2),
                            rowb + (y1c * W_ + x1c) * (C_ * 2));
    }
    __syncthreads();

    f32x4 acc[4][2];
#pragma unroll
    for (int mi = 0; mi < 4; ++mi)
#pragma unroll
        for (int nj = 0; nj < 2; ++nj)
#pragma unroll
            for (int r = 0; r < 4; ++r) acc[mi][nj][r] = 0.f;

    const uint4* wKf4 = (const uint4*)wKf;
    const char*  xTb  = (const char*)xT;
    const int    cof  = wv * 64;          // this wave's 32-channel byte window

    for (int tap = 0; tap < 9; ++tap) {
        const float4 wq = wgtv[lane * 9 + tap];
        const int4   iq = idxv[lane * 9 + tap];
        const char* p0 = xTb + iq.x + cof;
        const char* p1 = xTb + iq.y + cof;
        const char* p2 = xTb + iq.z + cof;
        const char* p3 = xTb + iq.w + cof;

        __syncthreads();                  // previous tap's A-frag reads complete
#pragma unroll
        for (int i = 0; i < 4; ++i) {     // 4 chunks of 8 channels
            const uint4 k0 = *(const uint4*)(p0 + i * 16);
            const uint4 k1 = *(const uint4*)(p1 + i * 16);
            const uint4 k2 = *(const uint4*)(p2 + i * 16);
            const uint4 k3 = *(const uint4*)(p3 + i * 16);
            float g0 = wq.x*bflo(k0.x) + wq.y*bflo(k1.x) + wq.z*bflo(k2.x) + wq.w*bflo(k3.x);
            float g1 = wq.x*bfhi(k0.x) + wq.y*bfhi(k1.x) + wq.z*bfhi(k2.x) + wq.w*bfhi(k3.x);
            float g2 = wq.x*bflo(k0.y) + wq.y*bflo(k1.y) + wq.z*bflo(k2.y) + wq.w*bflo(k3.y);
            float g3 = wq.x*bfhi(k0.y) + wq.y*bfhi(k1.y) + wq.z*bfhi(k2.y) + wq.w*bfhi(k3.y);
            float g4 = wq.x*bflo(k0.z) + wq.y*bflo(k1.z) + wq.z*bflo(k2.z) + wq.w*bflo(k3.z);
            float g5 = wq.x*bfhi(k0.z) + wq.y*bfhi(k1.z) + wq.z*bfhi(k2.z) + wq.w*bfhi(k3.z);
            float g6 = wq.x*bflo(k0.w) + wq.y*bflo(k1.w) + wq.z*bflo(k2.w) + wq.w*bflo(k3.w);
            float g7 = wq.x*bfhi(k0.w) + wq.y*bfhi(k1.w) + wq.z*bfhi(k2.w) + wq.w*bfhi(k3.w);
            uint4 pk;
            pk.x = pack2bf(g0, g1);
            pk.y = pack2bf(g2, g3);
            pk.z = pack2bf(g4, g5);
            pk.w = pack2bf(g6, g7);
            *(uint4*)&Abuf[wv][lane >> 4][(lane & 15) | (i << 4)][0] = pk;
        }
        __syncthreads();                  // tap's A tile visible

#pragma unroll
        for (int cc = 0; cc < 8; ++cc) {
            const int KC = tap * 8 + cc;
            uint4 braw[2];
#pragma unroll
            for (int nj = 0; nj < 2; ++nj) {
                const int NT = wv * 2 + nj;
                braw[nj] = wKf4[(size_t)(NT * 72 + KC) * 64 + lane];
            }
            bf16x8 a[4];
#pragma unroll
            for (int mi = 0; mi < 4; ++mi)
                a[mi] = *(const bf16x8*)&Abuf[cc][mi][lane][0];
#pragma unroll
            for (int nj = 0; nj < 2; ++nj) {
                bf16x8 bb = __builtin_bit_cast(bf16x8, braw[nj]);
#pragma unroll
                for (int mi = 0; mi < 4; ++mi)
                    acc[mi][nj] = __builtin_amdgcn_mfma_f32_16x16x32_bf16(
                        a[mi], bb, acc[mi][nj], 0, 0, 0);
            }
        }
    }

    // ---- epilogue: conv bias + BN + ReLU, float4 stores ----
#pragma unroll
    for (int nj = 0; nj < 2; ++nj) {
        const int o = wv * 32 + nj * 16 + (lane & 15);
        const float inv = gamma[o] * rsqrtf(rvar[o] + BN_EPS);
        const float sh  = beta[o] + (bias[o] - rmean[o]) * inv;
        float* ob = out + ((size_t)(b * O_ + o)) * HW_ + h * W_;
#pragma unroll
        for (int mi = 0; mi < 4; ++mi) {
            f32x4 v = acc[mi][nj];
            float4 r;
            r.x = fmaxf(v[0] * inv + sh, 0.f);
            r.y = fmaxf(v[1] * inv + sh, 0.f);
            r.z = fmaxf(v[2] * inv + sh, 0.f);
            r.w = fmaxf(v[3] * inv + sh, 0.f);
            *(float4*)&ob[mi * 16 + (lane >> 4) * 4] = r;
        }
    }
}

extern "C" void kernel_launch(void* const* d_in, const int* in_sizes, int n_in,
                              void* d_out, int out_size, void* d_ws, size_t ws_size,
                              hipStream_t stream) {
    const float* x     = (const float*)d_in[0];
    const float* w_off = (const float*)d_in[1];
    const float* b_off = (const float*)d_in[2];
    const float* w     = (const float*)d_in[3];
    const float* bias  = (const float*)d_in[4];
    const float* gamma = (const float*)d_in[5];
    const float* beta  = (const float*)d_in[6];
    const float* rmean = (const float*)d_in[7];
    const float* rvar  = (const float*)d_in[8];
    float* out = (float*)d_out;

    float*          om  = (float*)d_ws;                       // 884736 f32
    unsigned short* wKf = (unsigned short*)(om + 884736);     // 589824 bf16
    unsigned short* wof = wKf + 589824;                       // 73728 bf16
    unsigned short* xT  = wof + 73728;                        // 8388608 bf16

    repack_kernel<<<2592, 256, 0, stream>>>(w, w_off, wKf, wof);
    transpose_x_kernel<<<2048, 256, 0, stream>>>(x, xT);
    offset_mfma_kernel<<<512, 256, 0, stream>>>(xT, wof, b_off, om);
    dcn_mfma_kernel<<<512, 512, 0, stream>>>(
        xT, om, wKf, bias, gamma, beta, rmean, rvar, out);
}

// Round 6
// 184.004 us; speedup vs baseline: 11.6490x; 1.2276x over previous
//
#include <hip/hip_runtime.h>
#include <math.h>

#define B_   8
#define C_   256
#define H_   64
#define W_   64
#define O_   256
#define KK_  9
#define CK_  2304      // C_*KK_
#define HW_  4096      // H_*W_
#define BN_EPS 1e-5f

typedef __bf16 bf16x8 __attribute__((ext_vector_type(8)));
typedef float  f32x4  __attribute__((ext_vector_type(4)));

static __device__ __forceinline__ unsigned short f2bf(float f) {
    unsigned int u = __float_as_uint(f);
    unsigned int r = (u + 0x7fffu + ((u >> 16) & 1u)) >> 16;
    return (unsigned short)r;
}
static __device__ __forceinline__ float bflo(unsigned int u) {
    return __uint_as_float(u << 16);
}
static __device__ __forceinline__ float bfhi(unsigned int u) {
    return __uint_as_float(u & 0xffff0000u);
}
static __device__ __forceinline__ unsigned int pack2bf(float a, float b) {
    return (unsigned int)f2bf(a) | ((unsigned int)f2bf(b) << 16);
}

// ---- kernel 0: prep = transpose x -> xT (NHWC bf16), repack w -> wKf (B-frag
//      order, coalesced reads), repack w_off -> wof (frag order, zero-padded)
__global__ __launch_bounds__(256) void prep_kernel(
    const float* __restrict__ x, const float* __restrict__ w,
    const float* __restrict__ w_off,
    unsigned short* __restrict__ xT, unsigned short* __restrict__ wKf,
    unsigned short* __restrict__ wof)
{
    int blk = blockIdx.x;
    if (blk < 2048) {
        __shared__ float tile[64][65];
        const int b   = blk & 7;
        const int ct  = (blk >> 3) & 3;
        const int hwt = blk >> 5;
        const int c0  = ct * 64, hw0 = hwt * 64;
        const int tl  = threadIdx.x & 63, tg = threadIdx.x >> 6;
#pragma unroll
        for (int r = 0; r < 16; ++r) {
            int c_l = tg + r * 4;
            tile[c_l][tl] = x[((size_t)(b * C_ + c0 + c_l)) * HW_ + hw0 + tl];
        }
        __syncthreads();
#pragma unroll
        for (int r = 0; r < 16; ++r) {
            int hw_l = tg + r * 4;
            xT[((size_t)(b * HW_ + hw0 + hw_l)) * C_ + c0 + tl] = f2bf(tile[tl][hw_l]);
        }
    } else if (blk < 2048 + 2304) {
        int idx = (blk - 2048) * 256 + threadIdx.x;   // linear over w, coalesced read
        int o   = idx / CK_;
        int rem = idx - o * CK_;
        int c   = rem / 9;
        int tap = rem - c * 9;
        int NT  = o >> 4, n16 = o & 15;
        int kap = tap * 256 + c;
        int KC  = kap >> 5, kr = kap & 31;
        int lane = ((kr >> 3) << 4) | n16, e = kr & 7;
        wKf[((size_t)(NT * 72 + KC) * 64 + lane) * 8 + e] = f2bf(w[idx]);
    } else {
        int idx = (blk - 4352) * 256 + threadIdx.x;   // < 73728, dest-indexed
        int NT  = idx / 36864;
        int r   = idx - NT * 36864;
        int KC  = r >> 9;
        int r2  = r & 511;
        int lane = r2 >> 3, e = r2 & 7;
        int n16 = lane & 15, q = lane >> 4;
        int o   = NT * 16 + n16;
        int kap = KC * 32 + q * 8 + e;
        int tap = kap >> 8, c = kap & 255;
        wof[idx] = (o < 27) ? f2bf(w_off[(o * C_ + c) * KK_ + tap])
                            : (unsigned short)0;
    }
}

// ---- kernel 1: offset conv via MFMA, LDS-staged rows (coalesced A)
// grid 512 = (b = blk&7) x (h = blk>>3); 512 thr / 8 waves.
// wave wv: m-tile mi = wv&3 (16 px), n-tile nj = wv>>2 (16 t). K = 72 steps.
__global__ __launch_bounds__(512) void offset_mfma_kernel(
    const unsigned short* __restrict__ xT, const unsigned short* __restrict__ wof,
    const float* __restrict__ b_off, float* __restrict__ om)
{
    __shared__ unsigned short rowbuf[66 * 264];   // 66 px (1-px halo), stride 264

    const int blk = blockIdx.x;
    const int b = blk & 7, h = blk >> 3;
    const int tid = threadIdx.x, lane = tid & 63, wv = tid >> 6;
    const int mi = wv & 3, nj = wv >> 2;
    const int m16 = lane & 15, q = lane >> 4;

    f32x4 acc = {0.f, 0.f, 0.f, 0.f};
    const uint4* wof4 = (const uint4*)wof;

    for (int r = 0; r < 3; ++r) {
        const int hh = h - 1 + r;
        const bool vr = (hh >= 0) && (hh < H_);
        __syncthreads();                  // prior r's LDS reads complete
        if (vr) {
            const uint4* src = (const uint4*)&xT[((size_t)(b * HW_ + hh * W_)) * C_];
#pragma unroll
            for (int i = 0; i < 8; ++i) {
                int idx8 = i * 512 + tid;            // 8-elem chunks, linear
                int px = idx8 >> 5, c8 = (idx8 & 31) * 8;
                *(uint4*)&rowbuf[(px + 1) * 264 + c8] = src[idx8];
            }
        }
        if (tid < 33) {                   // zero left-halo row (px = -1)
            *(uint4*)&rowbuf[tid * 8] = make_uint4(0u, 0u, 0u, 0u);
        } else if (tid >= 256 && tid < 289) {   // zero right-halo row (px = 64)
            *(uint4*)&rowbuf[65 * 264 + (tid - 256) * 8] = make_uint4(0u, 0u, 0u, 0u);
        }
        __syncthreads();
        if (vr) {
            for (int s = 0; s < 3; ++s) {
                const unsigned short* arow = &rowbuf[(mi * 16 + m16 + s) * 264 + q * 8];
#pragma unroll
                for (int cc = 0; cc < 8; ++cc) {
                    bf16x8 a = *(const bf16x8*)&arow[cc * 32];
                    const int KC = (r * 3 + s) * 8 + cc;
                    uint4 braw = wof4[(size_t)(nj * 72 + KC) * 64 + lane];
                    acc = __builtin_amdgcn_mfma_f32_16x16x32_bf16(
                        a, __builtin_bit_cast(bf16x8, braw), acc, 0, 0, 0);
                }
            }
        }
    }

    const int t = nj * 16 + m16;
    if (t < 27) {
        const float bo = b_off[t];
        float s0 = acc[0] + bo, s1 = acc[1] + bo, s2 = acc[2] + bo, s3 = acc[3] + bo;
        if (t >= 18) {
            s0 = 1.f / (1.f + expf(-s0));
            s1 = 1.f / (1.f + expf(-s1));
            s2 = 1.f / (1.f + expf(-s2));
            s3 = 1.f / (1.f + expf(-s3));
        }
        float4 rr; rr.x = s0; rr.y = s1; rr.z = s2; rr.w = s3;
        *(float4*)&om[((size_t)(b * 27 + t)) * HW_ + h * W_ + mi * 16 + q * 4] = rr;
    }
}

// ---- kernel 2: fused sample (coalesced, lane=channel) + MFMA GEMM + BN + ReLU
// grid 512 = (b = blk&7) x (h = blk>>3). 512 thr / 8 waves.
// MFMA: wave wv = all 64 px (4 m-tiles) x o [wv*32, wv*32+32) (2 n-tiles).
// Sampling: wave wv feeds pixels [wv*8, wv*8+8); lane = channel-quad (4 ch, 8 B).
__global__ __launch_bounds__(512, 4) void dcn_mfma_kernel(
    const unsigned short* __restrict__ xT, const float* __restrict__ om,
    const unsigned short* __restrict__ wKf,
    const float* __restrict__ bias, const float* __restrict__ gamma,
    const float* __restrict__ beta, const float* __restrict__ rmean,
    const float* __restrict__ rvar, float* __restrict__ out)
{
    __shared__ float4 wgtv[576];                  // (px,tap): mod-folded bilinear weights
    __shared__ int4   idxv[576];                  // (px,tap): corner row-base BYTE offsets
    __shared__ __align__(16) unsigned short Abuf[8][4][64][8];   // [cc][mi][row'][j] 32 KB

    const int blk = blockIdx.x;
    const int b = blk & 7, h = blk >> 3;
    const int tid = threadIdx.x, lane = tid & 63, wv = tid >> 6;

    // ---- per-(pixel,tap) tables ----
    for (int i = tid; i < 576; i += 512) {
        int p = i / 9, t = i - p * 9;
        const int pos = h * W_ + p;
        float dy = om[(b * 27 +      t) * HW_ + pos];
        float dx = om[(b * 27 +  9 + t) * HW_ + pos];
        float md = om[(b * 27 + 18 + t) * HW_ + pos];
        float py = (float)(h - 1 + t / 3) + dy;
        float px = (float)(p - 1 + t % 3) + dx;
        float y0f = floorf(py), x0f = floorf(px);
        int   y0 = (int)y0f,    x0 = (int)x0f;
        float fy = py - y0f,    fx = px - x0f;
        int y0c = min(max(y0,     0), H_ - 1), y1c = min(max(y0 + 1, 0), H_ - 1);
        int x0c = min(max(x0,     0), W_ - 1), x1c = min(max(x0 + 1, 0), W_ - 1);
        float vy0 = (y0     >= 0 && y0     < H_) ? 1.f : 0.f;
        float vy1 = (y0 + 1 >= 0 && y0 + 1 < H_) ? 1.f : 0.f;
        float vx0 = (x0     >= 0 && x0     < W_) ? 1.f : 0.f;
        float vx1 = (x0 + 1 >= 0 && x0 + 1 < W_) ? 1.f : 0.f;
        wgtv[i] = make_float4((1.f - fy) * (1.f - fx) * vy0 * vx0 * md,
                              (1.f - fy) * fx         * vy0 * vx1 * md,
                              fy         * (1.f - fx) * vy1 * vx0 * md,
                              fy         * fx         * vy1 * vx1 * md);
        const int rowb = (b * HW_) * (C_ * 2);
        idxv[i] = make_int4(rowb + (y0c * W_ + x0c) * (C_ * 2),
                            rowb + (y0c * W_ + x1c) * (C_ * 2),
                            rowb + (y1c * W_ + x0c) * (C_ * 2),
                            rowb + (y1c * W_ + x1c) * (C_ * 2));
    }
    __syncthreads();

    f32x4 acc[4][2];
#pragma unroll
    for (int mi = 0; mi < 4; ++mi)
#pragma unroll
        for (int nj = 0; nj < 2; ++nj)
#pragma unroll
            for (int r = 0; r < 4; ++r) acc[mi][nj][r] = 0.f;

    const uint4* wKf4 = (const uint4*)wKf;
    const char*  xTb  = (const char*)xT;

    // sampling write-dest precompute (lane covers channels 4*lane .. 4*lane+3)
    const int s_cc = lane >> 3;                   // 32-ch chunk
    const int s_q2 = (lane >> 1) & 3;             // k-quad within chunk
    const int s_j0 = (lane & 1) * 4;              // element offset within frag row
    const int s_xr = (s_q2 << 1) ^ s_cc;          // XOR swizzle for bank spread
    const int s_mi = wv >> 1;                     // m-tile this wave's pixels fall in
    const int s_pb = (wv & 1) * 8;                // pixel base within m-tile
    const int loff = lane * 8;                    // byte offset within 512-B pixel row

    // MFMA-side read row (pre-XOR by cc inside loop)
    const int r_row = lane ^ ((lane >> 4) << 1);

    for (int tap = 0; tap < 9; ++tap) {
        // ---- sample 8 pixels: coalesced 512-B corner loads, weighted sum ----
        uint2 pk[8];
#pragma unroll
        for (int pp = 0; pp < 8; ++pp) {
            const int p = wv * 8 + pp;
            const int4   iq = idxv[p * 9 + tap];
            const float4 wq = wgtv[p * 9 + tap];
            const uint2 k0 = *(const uint2*)(xTb + iq.x + loff);
            const uint2 k1 = *(const uint2*)(xTb + iq.y + loff);
            const uint2 k2 = *(const uint2*)(xTb + iq.z + loff);
            const uint2 k3 = *(const uint2*)(xTb + iq.w + loff);
            float g0 = wq.x*bflo(k0.x) + wq.y*bflo(k1.x) + wq.z*bflo(k2.x) + wq.w*bflo(k3.x);
            float g1 = wq.x*bfhi(k0.x) + wq.y*bfhi(k1.x) + wq.z*bfhi(k2.x) + wq.w*bfhi(k3.x);
            float g2 = wq.x*bflo(k0.y) + wq.y*bflo(k1.y) + wq.z*bflo(k2.y) + wq.w*bflo(k3.y);
            float g3 = wq.x*bfhi(k0.y) + wq.y*bfhi(k1.y) + wq.z*bfhi(k2.y) + wq.w*bfhi(k3.y);
            pk[pp].x = pack2bf(g0, g1);
            pk[pp].y = pack2bf(g2, g3);
        }

        __syncthreads();                  // previous tap's A-frag reads complete
#pragma unroll
        for (int pp = 0; pp < 8; ++pp) {
            const int P   = s_pb + pp;                     // pixel & 15
            const int row = (P ^ s_xr) | (s_q2 << 4);      // swizzled frag row
            *(uint2*)&Abuf[s_cc][s_mi][row][s_j0] = pk[pp];
        }
        __syncthreads();                  // tap's A tile visible

        // ---- MFMA: 8 K-steps of 32 channels ----
#pragma unroll
        for (int cc = 0; cc < 8; ++cc) {
            const int KC = tap * 8 + cc;
            const int rr = r_row ^ cc;
            uint4 braw[2];
#pragma unroll
            for (int nj = 0; nj < 2; ++nj)
                braw[nj] = wKf4[(size_t)((wv * 2 + nj) * 72 + KC) * 64 + lane];
            bf16x8 a[4];
#pragma unroll
            for (int mi = 0; mi < 4; ++mi)
                a[mi] = *(const bf16x8*)&Abuf[cc][mi][rr][0];
#pragma unroll
            for (int nj = 0; nj < 2; ++nj) {
                bf16x8 bb = __builtin_bit_cast(bf16x8, braw[nj]);
#pragma unroll
                for (int mi = 0; mi < 4; ++mi)
                    acc[mi][nj] = __builtin_amdgcn_mfma_f32_16x16x32_bf16(
                        a[mi], bb, acc[mi][nj], 0, 0, 0);
            }
        }
    }

    // ---- epilogue: conv bias + BN + ReLU, float4 stores ----
#pragma unroll
    for (int nj = 0; nj < 2; ++nj) {
        const int o = wv * 32 + nj * 16 + (lane & 15);
        const float inv = gamma[o] * rsqrtf(rvar[o] + BN_EPS);
        const float sh  = beta[o] + (bias[o] - rmean[o]) * inv;
        float* ob = out + ((size_t)(b * O_ + o)) * HW_ + h * W_;
#pragma unroll
        for (int mi = 0; mi < 4; ++mi) {
            f32x4 v = acc[mi][nj];
            float4 r;
            r.x = fmaxf(v[0] * inv + sh, 0.f);
            r.y = fmaxf(v[1] * inv + sh, 0.f);
            r.z = fmaxf(v[2] * inv + sh, 0.f);
            r.w = fmaxf(v[3] * inv + sh, 0.f);
            *(float4*)&ob[mi * 16 + (lane >> 4) * 4] = r;
        }
    }
}

extern "C" void kernel_launch(void* const* d_in, const int* in_sizes, int n_in,
                              void* d_out, int out_size, void* d_ws, size_t ws_size,
                              hipStream_t stream) {
    const float* x     = (const float*)d_in[0];
    const float* w_off = (const float*)d_in[1];
    const float* b_off = (const float*)d_in[2];
    const float* w     = (const float*)d_in[3];
    const float* bias  = (const float*)d_in[4];
    const float* gamma = (const float*)d_in[5];
    const float* beta  = (const float*)d_in[6];
    const float* rmean = (const float*)d_in[7];
    const float* rvar  = (const float*)d_in[8];
    float* out = (float*)d_out;

    float*          om  = (float*)d_ws;                       // 884736 f32
    unsigned short* wKf = (unsigned short*)(om + 884736);     // 589824 bf16
    unsigned short* wof = wKf + 589824;                       // 73728 bf16
    unsigned short* xT  = wof + 73728;                        // 8388608 bf16

    prep_kernel<<<4640, 256, 0, stream>>>(x, w, w_off, xT, wKf, wof);
    offset_mfma_kernel<<<512, 512, 0, stream>>>(xT, wof, b_off, om);
    dcn_mfma_kernel<<<512, 512, 0, stream>>>(
        xT, om, wKf, bias, gamma, beta, rmean, rvar, out);
}